// Round 4
// baseline (629.402 us; speedup 1.0000x reference)
//
#include <hip/hip_runtime.h>
#include <hip/hip_cooperative_groups.h>
#include <stdint.h>

namespace cg = cooperative_groups;

typedef __attribute__((ext_vector_type(8))) short short8;
typedef __attribute__((ext_vector_type(4))) short short4v;
typedef __attribute__((ext_vector_type(4))) float float4v;

__device__ __forceinline__ unsigned short f2bf(float f) {
    union { float f; unsigned int u; } c; c.f = f;
    unsigned int x = c.u;
    unsigned int r = x + 0x7fffu + ((x >> 16) & 1u);   // RNE
    return (unsigned short)(r >> 16);
}
__device__ __forceinline__ void unpack2(unsigned int u, float& lo, float& hi) {
    union { unsigned int uu; float ff; } a, b;
    a.uu = u << 16;          // low bf16
    b.uu = u & 0xffff0000u;  // high bf16
    lo = a.ff; hi = b.ff;
}
__device__ __forceinline__ void acc8(uint4 v, float* s) {
    float a, b;
    unpack2(v.x, a, b); s[0] += a; s[1] += b;
    unpack2(v.y, a, b); s[2] += a; s[3] += b;
    unpack2(v.z, a, b); s[4] += a; s[5] += b;
    unpack2(v.w, a, b); s[6] += a; s[7] += b;
}

// ---- one node's aggregation: a = (1+eps)*h + sum_{j->i} h_j ; 16-lane quarter ----
__device__ __forceinline__ void aggr_node(int node, int li,
                                          const uint4* __restrict__ Hin,
                                          const int* __restrict__ off,
                                          const int* __restrict__ esrc,
                                          float ep, uint4* __restrict__ Ahi) {
    uint4 ow = Hin[node * 16 + li];
    float s[8] = {0.f, 0.f, 0.f, 0.f, 0.f, 0.f, 0.f, 0.f};
    int i = off[node], e = off[node + 1];
    int idx[8];
    if (i + 8 <= e) {
#pragma unroll
        for (int j = 0; j < 8; ++j) idx[j] = esrc[i + j];
    }
    while (i + 8 <= e) {
        uint4 v[8];
#pragma unroll
        for (int j = 0; j < 8; ++j) v[j] = Hin[idx[j] * 16 + li];
        int inext = i + 8;
        if (inext + 8 <= e) {
#pragma unroll
            for (int j = 0; j < 8; ++j) idx[j] = esrc[inext + j];
        }
#pragma unroll
        for (int j = 0; j < 8; ++j) acc8(v[j], s);
        i = inext;
    }
    if (i < e) {                            // predicated tail batch
        int last = e - 1;
        uint4 v[8];
#pragma unroll
        for (int j = 0; j < 8; ++j) {
            int k = i + j;
            int cl = k < last ? k : last;
            v[j] = Hin[esrc[cl] * 16 + li];
        }
#pragma unroll
        for (int j = 0; j < 8; ++j) {
            bool ok = (i + j) < e;
            uint4 u2;
            u2.x = ok ? v[j].x : 0u;
            u2.y = ok ? v[j].y : 0u;
            u2.z = ok ? v[j].z : 0u;
            u2.w = ok ? v[j].w : 0u;
            acc8(u2, s);
        }
    }
    float o[8];
    unpack2(ow.x, o[0], o[1]);
    unpack2(ow.y, o[2], o[3]);
    unpack2(ow.z, o[4], o[5]);
    unpack2(ow.w, o[6], o[7]);
#pragma unroll
    for (int k = 0; k < 8; ++k) s[k] = ep * o[k] + s[k];
    uint4 r;
    r.x = ((unsigned int)f2bf(s[1]) << 16) | f2bf(s[0]);
    r.y = ((unsigned int)f2bf(s[3]) << 16) | f2bf(s[2]);
    r.z = ((unsigned int)f2bf(s[5]) << 16) | f2bf(s[4]);
    r.w = ((unsigned int)f2bf(s[7]) << 16) | f2bf(s[6]);
    Ahi[node * 16 + li] = r;
}

// ---- MLP phase: 512 threads; 256-row tile-pair per block iteration ----
template <int NT2, bool LOGITS>
__device__ void mlp_phase(short* wbuf,
                          const unsigned short* __restrict__ AhiS,
                          const unsigned short* __restrict__ W1h, const float* __restrict__ B1,
                          const unsigned short* __restrict__ W2h, const float* __restrict__ B2,
                          unsigned short* __restrict__ HOut, float* __restrict__ LOut, int M) {
    int t = threadIdx.x, w = t >> 6, lane = t & 63;
    int lm = lane & 15, lg = lane >> 4;
    int h = w >> 2, wq = w & 3;
    int nTP = (M + 255) / 256;
    for (int tp = blockIdx.x; tp < nTP; tp += gridDim.x) {
        __syncthreads();               // wbuf reuse guard (prev iter / prev phase)
        int rbase = tp * 256 + h * 128;

        short8 xf2[2][4];
        bool act[2];
#pragma unroll
        for (int t2 = 0; t2 < 2; ++t2) {
            int r0 = rbase + t2 * 64 + wq * 16;
            act[t2] = (r0 < M);            // wave-uniform (M % 16 == 0)
            if (act[t2]) {
                const short* Xp = (const short*)AhiS + (r0 + lm) * 128 + lg * 8;
#pragma unroll
                for (int kb = 0; kb < 4; ++kb) xf2[t2][kb] = *(const short8*)(Xp + kb * 32);
            } else {
#pragma unroll
                for (int kb = 0; kb < 4; ++kb) xf2[t2][kb] = (short8){0,0,0,0,0,0,0,0};
            }
        }
        constexpr int WTOT2 = NT2 * 16 * 128;               // shorts
        constexpr int W2CH = (WTOT2 + 4095) / 4096;         // 4 or 2
        short8 w1r[4], w2r[W2CH];
#pragma unroll
        for (int u = 0; u < 4; ++u) w1r[u] = *(const short8*)(W1h + t * 8 + u * 4096);
#pragma unroll
        for (int u = 0; u < W2CH; ++u) {
            int i = t * 8 + u * 4096;
            if (i < WTOT2) w2r[u] = *(const short8*)(W2h + i);
        }

        // stage W1
#pragma unroll
        for (int u = 0; u < 4; ++u) {
            int i = t * 8 + u * 4096;
            *(short8*)&wbuf[(i >> 7) * 136 + (i & 127)] = w1r[u];
        }
        __syncthreads();

        // GEMM1 (a = W1 frag, b = node frag -> D = H^T), pack H in registers
        short4v h2[2][8];
#pragma unroll
        for (int t2 = 0; t2 < 2; ++t2) {
            float4v acc1[8];
#pragma unroll
            for (int nt = 0; nt < 8; ++nt) acc1[nt] = (float4v){0.f, 0.f, 0.f, 0.f};
#pragma unroll
            for (int nt = 0; nt < 8; ++nt) {
#pragma unroll
                for (int kb = 0; kb < 4; ++kb) {
                    short8 wf = *(const short8*)&wbuf[(nt * 16 + lm) * 136 + kb * 32 + lg * 8];
                    acc1[nt] = __builtin_amdgcn_mfma_f32_16x16x32_bf16(wf, xf2[t2][kb], acc1[nt], 0, 0, 0);
                }
            }
#pragma unroll
            for (int nt = 0; nt < 8; ++nt) {
                float4 b1 = *(const float4*)(B1 + nt * 16 + lg * 4);
                float v0 = acc1[nt][0] + b1.x; v0 = v0 > 0.f ? v0 : 0.f;
                float v1 = acc1[nt][1] + b1.y; v1 = v1 > 0.f ? v1 : 0.f;
                float v2 = acc1[nt][2] + b1.z; v2 = v2 > 0.f ? v2 : 0.f;
                float v3 = acc1[nt][3] + b1.w; v3 = v3 > 0.f ? v3 : 0.f;
                h2[t2][nt] = (short4v){(short)f2bf(v0), (short)f2bf(v1),
                                       (short)f2bf(v2), (short)f2bf(v3)};
            }
        }

        __syncthreads();
        // stage W2
#pragma unroll
        for (int u = 0; u < W2CH; ++u) {
            int i = t * 8 + u * 4096;
            if (i < WTOT2) *(short8*)&wbuf[(i >> 7) * 136 + (i & 127)] = w2r[u];
        }
        __syncthreads();

        // GEMM2: K=16 MFMAs consume h2 directly
        float4v acc2[2][NT2];
#pragma unroll
        for (int t2 = 0; t2 < 2; ++t2)
#pragma unroll
            for (int ot = 0; ot < NT2; ++ot) acc2[t2][ot] = (float4v){0.f, 0.f, 0.f, 0.f};
#pragma unroll
        for (int ot = 0; ot < NT2; ++ot) {
#pragma unroll
            for (int nt = 0; nt < 8; ++nt) {
                short4v wf = *(const short4v*)&wbuf[(ot * 16 + lm) * 136 + nt * 16 + lg * 4];
#pragma unroll
                for (int t2 = 0; t2 < 2; ++t2)
                    acc2[t2][ot] = __builtin_amdgcn_mfma_f32_16x16x16bf16_1k(wf, h2[t2][nt],
                                                                             acc2[t2][ot], 0, 0, 0);
            }
        }

        // epilogue
#pragma unroll
        for (int t2 = 0; t2 < 2; ++t2) {
            if (!act[t2]) continue;
            int row = rbase + t2 * 64 + wq * 16 + lm;
            if (!LOGITS) {
#pragma unroll
                for (int ot = 0; ot < NT2; ++ot) {
                    float4 b2 = *(const float4*)(B2 + ot * 16 + lg * 4);
                    float v0 = acc2[t2][ot][0] + b2.x; v0 = v0 > 0.f ? v0 : 0.f;
                    float v1 = acc2[t2][ot][1] + b2.y; v1 = v1 > 0.f ? v1 : 0.f;
                    float v2 = acc2[t2][ot][2] + b2.z; v2 = v2 > 0.f ? v2 : 0.f;
                    float v3 = acc2[t2][ot][3] + b2.w; v3 = v3 > 0.f ? v3 : 0.f;
                    uint2 pk;
                    pk.x = ((unsigned int)f2bf(v1) << 16) | f2bf(v0);
                    pk.y = ((unsigned int)f2bf(v3) << 16) | f2bf(v2);
                    *(uint2*)(HOut + row * 128 + ot * 16 + lg * 4) = pk;
                }
            } else {
                float vv[NT2][4];
#pragma unroll
                for (int ot = 0; ot < NT2; ++ot) {
                    int ub = ot * 16 + lg * 4;
                    bool valid = ub <= 36;
                    float4 b2 = valid ? *(const float4*)(B2 + ub) : (float4){0.f, 0.f, 0.f, 0.f};
                    vv[ot][0] = valid ? acc2[t2][ot][0] + b2.x : -1e30f;
                    vv[ot][1] = valid ? acc2[t2][ot][1] + b2.y : -1e30f;
                    vv[ot][2] = valid ? acc2[t2][ot][2] + b2.z : -1e30f;
                    vv[ot][3] = valid ? acc2[t2][ot][3] + b2.w : -1e30f;
                }
                float m = -1e30f;
#pragma unroll
                for (int ot = 0; ot < NT2; ++ot)
#pragma unroll
                    for (int r = 0; r < 4; ++r) m = fmaxf(m, vv[ot][r]);
                m = fmaxf(m, __shfl_xor(m, 16, 64));
                m = fmaxf(m, __shfl_xor(m, 32, 64));
                float s = 0.f;
#pragma unroll
                for (int ot = 0; ot < NT2; ++ot)
#pragma unroll
                    for (int r = 0; r < 4; ++r)
                        s += (vv[ot][r] > -1e29f) ? expf(vv[ot][r] - m) : 0.f;
                s += __shfl_xor(s, 16, 64);
                s += __shfl_xor(s, 32, 64);
                float ls = m + logf(s);
#pragma unroll
                for (int ot = 0; ot < NT2; ++ot) {
                    int ub = ot * 16 + lg * 4;
                    if (ub <= 36) {
                        float4 outv = {vv[ot][0] - ls, vv[ot][1] - ls,
                                       vv[ot][2] - ls, vv[ot][3] - ls};
                        *(float4*)(LOut + row * 40 + ub) = outv;
                    }
                }
            }
        }
    }
}

// ==================== cooperative dispatch 1: prep + CSR build ====================
struct PrepCsrP {
    const float* W[6];
    unsigned short* hi[6];
    const float4* xin;
    uint2* xout;
    int n4;
    const int* esrc_in;
    const int* edst_in;
    int nE;
    int* bucketCnt;     // 512
    int* bucketBase;    // 513
    int* bucketCur;     // 512
    int* off;           // M+1
    unsigned int* ebuf; // nE
    int* esrc;          // nE
    int M;
    int nChunk;
    int nBk;
    int* aggrCtr;       // 3
};

// XCD L2s are not cross-coherent: every grid.sync must be bracketed by
// __threadfence() (release: buffer_wbl2 sc1) BEFORE and (acquire: buffer_inv sc1)
// AFTER, else plain reads hit stale L2 lines (this was round-3's failure).
#define GSYNC(g) do { __threadfence(); (g).sync(); __threadfence(); } while (0)

__global__ __launch_bounds__(512, 4) void k_prepcsr(PrepCsrP p) {
    cg::grid_group grid = cg::this_grid();
    __shared__ char smem[30720];
    int b = blockIdx.x, t = threadIdx.x, nb = gridDim.x;

    // ---- P0: zero counters; weight convert+transpose; x convert ----
    if (b == 0) {
        p.bucketCnt[t] = 0;
        if (t < 3) p.aggrCtr[t] = 0;
    }
#pragma unroll
    for (int mat = 0; mat < 6; ++mat) {
        int NPAD = (mat == 5) ? 48 : 128;
        int N = (mat == 5) ? 40 : 128;
        int tot = NPAD * 128;
        for (int i = b * 512 + t; i < tot; i += nb * 512) {
            int n = i >> 7, k = i & 127;
            float w = (n < N) ? p.W[mat][k * N + n] : 0.f;
            p.hi[mat][i] = f2bf(w);
        }
    }
    for (int i = b * 512 + t; i < p.n4; i += nb * 512) {
        float4 v = p.xin[i];
        uint2 o;
        o.x = ((unsigned int)f2bf(v.y) << 16) | f2bf(v.x);
        o.y = ((unsigned int)f2bf(v.w) << 16) | f2bf(v.z);
        p.xout[i] = o;
    }
    GSYNC(grid);

    // ---- P1: histogram ----
    {
        int* c = (int*)smem;
        for (int ch = b; ch < p.nChunk; ch += nb) {
            c[t] = 0;
            __syncthreads();
            int base = ch * 4096;
            for (int i = t; i < 4096; i += 512) {
                int e = base + i;
                if (e < p.nE) atomicAdd(&c[p.edst_in[e] >> 8], 1);
            }
            __syncthreads();
            if (c[t]) atomicAdd(&p.bucketCnt[t], c[t]);
            __syncthreads();
        }
    }
    GSYNC(grid);

    // ---- P2: scan (block 0 only) ----
    if (b == 0) {
        int* s = (int*)smem;
        int v = p.bucketCnt[t];
        s[t] = v;
        __syncthreads();
        for (int o = 1; o < 512; o <<= 1) {
            int x = (t >= o) ? s[t - o] : 0;
            __syncthreads();
            s[t] += x;
            __syncthreads();
        }
        p.bucketBase[t] = s[t] - v;
        p.bucketCur[t] = s[t] - v;
        if (t == 511) p.bucketBase[512] = s[511];
        if (t == 0) p.off[p.M] = p.nE;
    }
    GSYNC(grid);

    // ---- P3: scatter (packed entry: src | (dst&255)<<17) ----
    {
        int* cnt = (int*)smem;
        int* excl = cnt + 512;
        int* chunk = excl + 512;
        unsigned int* buf = (unsigned int*)(chunk + 512);
        unsigned short* bkt = (unsigned short*)(buf + 4096);
        for (int ch = b; ch < p.nChunk; ch += nb) {
            cnt[t] = 0;
            __syncthreads();
            int base = ch * 4096;
            int n = p.nE - base; if (n > 4096) n = 4096;
            unsigned int pk[8]; int bk[8]; int rk[8];
#pragma unroll
            for (int u = 0; u < 8; ++u) {
                int i = t + u * 512;
                if (i < n) {
                    int e = base + i;
                    int d = p.edst_in[e];
                    int bb = d >> 8;
                    bk[u] = bb;
                    pk[u] = (unsigned int)p.esrc_in[e] | ((unsigned int)(d & 255) << 17);
                    rk[u] = atomicAdd(&cnt[bb], 1);
                } else bk[u] = -1;
            }
            __syncthreads();
            excl[t] = cnt[t];
            __syncthreads();
            for (int o = 1; o < 512; o <<= 1) {
                int x = (t >= o) ? excl[t - o] : 0;
                __syncthreads();
                excl[t] += x;
                __syncthreads();
            }
            int ex = excl[t] - cnt[t];
            __syncthreads();
            excl[t] = ex;
            if (cnt[t]) chunk[t] = atomicAdd(&p.bucketCur[t], cnt[t]);
            __syncthreads();
#pragma unroll
            for (int u = 0; u < 8; ++u) {
                if (bk[u] >= 0) {
                    int lp = excl[bk[u]] + rk[u];
                    buf[lp] = pk[u];
                    bkt[lp] = (unsigned short)bk[u];
                }
            }
            __syncthreads();
            for (int i = t; i < n; i += 512) {
                int bb = bkt[i];
                p.ebuf[chunk[bb] + (i - excl[bb])] = buf[i];
            }
            __syncthreads();
        }
    }
    GSYNC(grid);

    // ---- P4: build per-node CSR within each bucket ----
    {
        int* cnt = (int*)smem;
        int* excl = cnt + 256;
        int* obuf = excl + 256;
        for (int bb = b; bb < p.nBk; bb += nb) {
            int base = p.bucketBase[bb];
            int n = p.bucketBase[bb + 1] - base;
            if (t < 256) cnt[t] = 0;
            __syncthreads();
            unsigned int pk[10]; int dl[10]; int rk[10];
#pragma unroll
            for (int u = 0; u < 10; ++u) {
                int i = t + u * 512;
                if (i < n) {
                    unsigned int pw = p.ebuf[base + i];
                    pk[u] = pw;
                    int d = (pw >> 17) & 255;
                    dl[u] = d;
                    rk[u] = atomicAdd(&cnt[d], 1);
                } else dl[u] = -1;
            }
            __syncthreads();
            if (t < 256) excl[t] = cnt[t];
            __syncthreads();
            for (int o = 1; o < 256; o <<= 1) {
                int x = (t < 256 && t >= o) ? excl[t - o] : 0;
                __syncthreads();
                if (t < 256) excl[t] += x;
                __syncthreads();
            }
            if (t < 256) {
                int ex = excl[t] - cnt[t];
                int node = bb * 256 + t;
                if (node < p.M) p.off[node] = base + ex;
                excl[t] = ex;
            }
            __syncthreads();
#pragma unroll
            for (int u = 0; u < 10; ++u) {
                if (dl[u] >= 0) {
                    int lp = excl[dl[u]] + rk[u];
                    if (lp < 5120) obuf[lp] = (int)(pk[u] & 0x1FFFF);
                }
            }
            __syncthreads();
            for (int i = t; i < n; i += 512) p.esrc[base + i] = obuf[i];
            __syncthreads();
        }
    }
}

// ==================== cooperative dispatch 2: all 3 GIN layers ====================
__device__ void aggr_queue(const uint4* __restrict__ Hin, const int* __restrict__ off,
                           const int* __restrict__ esrc, const float* __restrict__ epsp,
                           uint4* __restrict__ Ahi, int M, int* __restrict__ ctr) {
    __shared__ int sg;
    int w = threadIdx.x >> 6, lane = threadIdx.x & 63;
    int li = lane & 15, q = lane >> 4;
    float ep = 1.0f + epsp[0];
    int nGrp = (M + 31) / 32;
    while (true) {
        __syncthreads();
        if (threadIdx.x == 0) sg = atomicAdd(ctr, 1);
        __syncthreads();
        int g = sg;
        if (g >= nGrp) break;
        int node = g * 32 + w * 4 + q;
        if (node < M) aggr_node(node, li, Hin, off, esrc, ep, Ahi);
    }
}

struct LayersP {
    const uint4* xb;       // layer0 input; reused as layer1 MLP output
    uint4* Ahi;
    uint4* Hb;
    const int* off;
    const int* esrc;
    const float* eps0; const float* eps1; const float* eps2;
    const unsigned short* W1_0; const float* B1_0; const unsigned short* W2_0; const float* B2_0;
    const unsigned short* W1_1; const float* B1_1; const unsigned short* W2_1; const float* B2_1;
    const unsigned short* W1_2; const float* B1_2; const unsigned short* W2_2; const float* B2_2;
    float* out;
    int M;
    int* aggrCtr;          // 3, zeroed by k_prepcsr each launch
};

__global__ __launch_bounds__(512, 4) void k_layers(LayersP L) {
    cg::grid_group grid = cg::this_grid();
    __shared__ short wbuf[128 * 136];
    // layer 0: xb --aggr--> Ahi --mlp--> Hb
    aggr_queue(L.xb, L.off, L.esrc, L.eps0, L.Ahi, L.M, L.aggrCtr + 0);
    GSYNC(grid);
    mlp_phase<8, false>(wbuf, (const unsigned short*)L.Ahi, L.W1_0, L.B1_0, L.W2_0, L.B2_0,
                        (unsigned short*)L.Hb, nullptr, L.M);
    GSYNC(grid);
    // layer 1: Hb --aggr--> Ahi --mlp--> xb
    aggr_queue((const uint4*)L.Hb, L.off, L.esrc, L.eps1, L.Ahi, L.M, L.aggrCtr + 1);
    GSYNC(grid);
    mlp_phase<8, false>(wbuf, (const unsigned short*)L.Ahi, L.W1_1, L.B1_1, L.W2_1, L.B2_1,
                        (unsigned short*)L.xb, nullptr, L.M);
    GSYNC(grid);
    // layer 2: xb --aggr--> Ahi --mlp--> logits (log_softmax fused)
    aggr_queue(L.xb, L.off, L.esrc, L.eps2, L.Ahi, L.M, L.aggrCtr + 2);
    GSYNC(grid);
    mlp_phase<3, true>(wbuf, (const unsigned short*)L.Ahi, L.W1_2, L.B1_2, L.W2_2, L.B2_2,
                       nullptr, L.out, L.M);
}

// ==================== fallback pipeline (round-2, non-cooperative) ====================
struct FbPrep {
    const float* W[6];
    unsigned short* hi[6];
    const float4* xin;
    uint2* xout;
    int n4;
    int nxBlocks;
    const int* dst;
    int nE;
    int* bucketCnt;
};

__global__ __launch_bounds__(256) void fb_prep(FbPrep p) {
    __shared__ int c[512];
    int b = blockIdx.x;
    int t = threadIdx.x;
    if (b < 344) {
        int mat = b >> 6;
        int rel = b - mat * 64;
        int NPAD = (mat == 5) ? 48 : 128;
        int N = (mat == 5) ? 40 : 128;
        int idx = rel * 256 + t;
        if (idx >= NPAD * 128) return;
        int n = idx >> 7, k = idx & 127;
        float w = (n < N) ? p.W[mat][k * N + n] : 0.f;
        p.hi[mat][idx] = f2bf(w);
    } else if (b < 344 + p.nxBlocks) {
        int i = (b - 344) * 256 + t;
        if (i >= p.n4) return;
        float4 v = p.xin[i];
        uint2 o;
        o.x = ((unsigned int)f2bf(v.y) << 16) | f2bf(v.x);
        o.y = ((unsigned int)f2bf(v.w) << 16) | f2bf(v.z);
        p.xout[i] = o;
    } else {
        for (int i = t; i < 512; i += 256) c[i] = 0;
        __syncthreads();
        int base = (b - 344 - p.nxBlocks) * 4096;
        for (int i = t; i < 4096; i += 256) {
            int e = base + i;
            if (e < p.nE) atomicAdd(&c[p.dst[e] >> 8], 1);
        }
        __syncthreads();
        for (int i = t; i < 512; i += 256)
            if (c[i]) atomicAdd(&p.bucketCnt[i], c[i]);
    }
}

__global__ __launch_bounds__(512) void bs_scan(const int* __restrict__ bucketCnt,
                                               int* __restrict__ bucketBase,
                                               int* __restrict__ bucketCur,
                                               int* __restrict__ off, int M, int nE) {
    __shared__ int s[512];
    int t = threadIdx.x;
    int v = bucketCnt[t];
    s[t] = v;
    __syncthreads();
    for (int o = 1; o < 512; o <<= 1) {
        int x = (t >= o) ? s[t - o] : 0;
        __syncthreads();
        s[t] += x;
        __syncthreads();
    }
    bucketBase[t] = s[t] - v;
    bucketCur[t] = s[t] - v;
    if (t == 511) bucketBase[512] = s[511];
    if (t == 0) off[M] = nE;
}

__global__ __launch_bounds__(512) void bs_scatter(const int* __restrict__ src,
                                                  const int* __restrict__ dst, int nE,
                                                  int* __restrict__ bucketCur,
                                                  unsigned int* __restrict__ ebuf) {
    __shared__ int cnt[512];
    __shared__ int excl[512];
    __shared__ int chunk[512];
    __shared__ unsigned int buf[4096];
    __shared__ unsigned short bkt[4096];
    int t = threadIdx.x;
    cnt[t] = 0;
    __syncthreads();
    int base = blockIdx.x * 4096;
    int n = nE - base; if (n > 4096) n = 4096;
    unsigned int pk[8]; int bk[8]; int rk[8];
#pragma unroll
    for (int u = 0; u < 8; ++u) {
        int i = t + u * 512;
        if (i < n) {
            int e = base + i;
            int d = dst[e];
            int b = d >> 8;
            bk[u] = b;
            pk[u] = (unsigned int)src[e] | ((unsigned int)(d & 255) << 17);
            rk[u] = atomicAdd(&cnt[b], 1);
        } else bk[u] = -1;
    }
    __syncthreads();
    excl[t] = cnt[t];
    __syncthreads();
    for (int o = 1; o < 512; o <<= 1) {
        int x = (t >= o) ? excl[t - o] : 0;
        __syncthreads();
        excl[t] += x;
        __syncthreads();
    }
    int ex = excl[t] - cnt[t];
    __syncthreads();
    excl[t] = ex;
    if (cnt[t]) chunk[t] = atomicAdd(&bucketCur[t], cnt[t]);
    __syncthreads();
#pragma unroll
    for (int u = 0; u < 8; ++u) {
        if (bk[u] >= 0) {
            int lp = excl[bk[u]] + rk[u];
            buf[lp] = pk[u];
            bkt[lp] = (unsigned short)bk[u];
        }
    }
    __syncthreads();
    for (int i = t; i < n; i += 512) {
        int b = bkt[i];
        ebuf[chunk[b] + (i - excl[b])] = buf[i];
    }
}

__global__ __launch_bounds__(512) void bs_build(const unsigned int* __restrict__ ebuf,
                                                const int* __restrict__ bucketBase,
                                                int* __restrict__ off,
                                                int* __restrict__ esrc, int M) {
    __shared__ int cnt[256];
    __shared__ int excl[256];
    __shared__ int obuf[5120];
    int t = threadIdx.x, b = blockIdx.x;
    int base = bucketBase[b];
    int n = bucketBase[b + 1] - base;
    if (t < 256) cnt[t] = 0;
    __syncthreads();
    unsigned int pk[10]; int dl[10]; int rk[10];
#pragma unroll
    for (int u = 0; u < 10; ++u) {
        int i = t + u * 512;
        if (i < n) {
            unsigned int p = ebuf[base + i];
            pk[u] = p;
            int d = (p >> 17) & 255;
            dl[u] = d;
            rk[u] = atomicAdd(&cnt[d], 1);
        } else dl[u] = -1;
    }
    __syncthreads();
    if (t < 256) excl[t] = cnt[t];
    __syncthreads();
    for (int o = 1; o < 256; o <<= 1) {
        int x = (t < 256 && t >= o) ? excl[t - o] : 0;
        __syncthreads();
        if (t < 256) excl[t] += x;
        __syncthreads();
    }
    if (t < 256) {
        int ex = excl[t] - cnt[t];
        int node = b * 256 + t;
        if (node < M) off[node] = base + ex;
        excl[t] = ex;
    }
    __syncthreads();
#pragma unroll
    for (int u = 0; u < 10; ++u) {
        if (dl[u] >= 0) {
            int lp = excl[dl[u]] + rk[u];
            if (lp < 5120) obuf[lp] = (int)(pk[u] & 0x1FFFF);
        }
    }
    __syncthreads();
    for (int i = t; i < n; i += 512) esrc[base + i] = obuf[i];
}

__global__ __launch_bounds__(256) void fb_aggr(const uint4* __restrict__ Hin,
                                               const int* __restrict__ off,
                                               const int* __restrict__ esrc,
                                               const float* __restrict__ epsp,
                                               uint4* __restrict__ Ahi, int M) {
    int w = threadIdx.x >> 6, lane = threadIdx.x & 63;
    int li = lane & 15, q = lane >> 4;
    int node = blockIdx.x * 16 + w * 4 + q;
    if (node >= M) return;
    aggr_node(node, li, Hin, off, esrc, 1.0f + epsp[0], Ahi);
}

template <int NT2, bool LOGITS>
__global__ __launch_bounds__(512, 4) void fb_mlp(const unsigned short* __restrict__ AhiS,
                                                 const unsigned short* __restrict__ W1h,
                                                 const float* __restrict__ B1,
                                                 const unsigned short* __restrict__ W2h,
                                                 const float* __restrict__ B2,
                                                 unsigned short* __restrict__ HOut,
                                                 float* __restrict__ LOut, int M) {
    __shared__ short wbuf[128 * 136];
    mlp_phase<NT2, LOGITS>(wbuf, AhiS, W1h, B1, W2h, B2, HOut, LOut, M);
}

// ---- cooperative-launch preflight probe ----
__global__ void k_probe(int x) { (void)x; }

// ---------------- launch ----------------
extern "C" void kernel_launch(void* const* d_in, const int* in_sizes, int n_in,
                              void* d_out, int out_size, void* d_ws, size_t ws_size,
                              hipStream_t stream) {
    const float* x    = (const float*)d_in[0];
    const int*   edges = (const int*)d_in[1];

    int M  = in_sizes[0] / 128;   // 100000
    int nE = in_sizes[1] / 2;     // 1600000
    const int* e_src = edges;
    const int* e_dst = edges + nE;

    char* ws = (char*)d_ws;
    size_t o = 0;
    auto alloc = [&](size_t bytes) {
        size_t p = o;
        o = (o + bytes + 511) & ~(size_t)511;
        return ws + p;
    };
    int* bucketCnt  = (int*)alloc(512 * 4);
    int* bucketBase = (int*)alloc(513 * 4);
    int* bucketCur  = (int*)alloc(512 * 4);
    int* aggrCtr    = (int*)alloc(3 * 4);
    int* off  = (int*)alloc((size_t)(M + 1) * 4);
    int* esrc = (int*)alloc((size_t)nE * 4);
    unsigned int* ebuf = (unsigned int*)alloc((size_t)nE * 4);

    PrepCsrP pc;
    pc.W[0] = (const float*)d_in[2];  pc.W[1] = (const float*)d_in[4];
    pc.W[2] = (const float*)d_in[7];  pc.W[3] = (const float*)d_in[9];
    pc.W[4] = (const float*)d_in[12]; pc.W[5] = (const float*)d_in[14];
    for (int m = 0; m < 6; ++m) {
        int npad = (m == 5) ? 48 : 128;
        pc.hi[m] = (unsigned short*)alloc((size_t)npad * 128 * 2);
    }
    unsigned short* xb  = (unsigned short*)alloc((size_t)M * 128 * 2);
    unsigned short* Ahi = (unsigned short*)alloc((size_t)M * 128 * 2);
    unsigned short* Hb  = (unsigned short*)alloc((size_t)M * 128 * 2);
    pc.xin = (const float4*)x;
    pc.xout = (uint2*)xb;
    pc.n4 = M * 32;
    pc.esrc_in = e_src;
    pc.edst_in = e_dst;
    pc.nE = nE;
    pc.bucketCnt = bucketCnt;
    pc.bucketBase = bucketBase;
    pc.bucketCur = bucketCur;
    pc.off = off;
    pc.ebuf = ebuf;
    pc.esrc = esrc;
    pc.M = M;
    pc.nChunk = (nE + 4095) / 4096;   // 391
    pc.nBk = (M + 255) / 256;         // 391
    pc.aggrCtr = aggrCtr;
    (void)ws_size; (void)n_in; (void)out_size;

    LayersP Ls;
    Ls.xb = (const uint4*)xb;
    Ls.Ahi = (uint4*)Ahi;
    Ls.Hb = (uint4*)Hb;
    Ls.off = off;
    Ls.esrc = esrc;
    Ls.eps0 = (const float*)d_in[6];
    Ls.eps1 = (const float*)d_in[11];
    Ls.eps2 = (const float*)d_in[16];
    Ls.W1_0 = pc.hi[0]; Ls.B1_0 = (const float*)d_in[3];
    Ls.W2_0 = pc.hi[1]; Ls.B2_0 = (const float*)d_in[5];
    Ls.W1_1 = pc.hi[2]; Ls.B1_1 = (const float*)d_in[8];
    Ls.W2_1 = pc.hi[3]; Ls.B2_1 = (const float*)d_in[10];
    Ls.W1_2 = pc.hi[4]; Ls.B1_2 = (const float*)d_in[13];
    Ls.W2_2 = pc.hi[5]; Ls.B2_2 = (const float*)d_in[15];
    Ls.out = (float*)d_out;
    Ls.M = M;
    Ls.aggrCtr = aggrCtr;

    // one-time preflight: can this runtime do cooperative launches? (private
    // non-blocking stream so a failure cannot poison the harness's capture)
    static int g_coop = -1;
    if (g_coop < 0) {
        g_coop = 0;
        hipStream_t ps;
        if (hipStreamCreateWithFlags(&ps, hipStreamNonBlocking) == hipSuccess) {
            int zero = 0;
            void* pa[] = { &zero };
            if (hipLaunchCooperativeKernel((const void*)k_probe, dim3(2), dim3(64),
                                           pa, 0, ps) == hipSuccess)
                g_coop = 1;
            // intentionally leak ps: no sync/destroy during possible capture
        }
    }

    bool done = false;
    if (g_coop == 1) {
        void* a1[] = { &pc };
        void* a2[] = { &Ls };
        hipError_t e1 = hipLaunchCooperativeKernel((const void*)k_prepcsr,
                                                   dim3(pc.nChunk), dim3(512), a1, 0, stream);
        hipError_t e2 = hipSuccess;
        if (e1 == hipSuccess)
            e2 = hipLaunchCooperativeKernel((const void*)k_layers,
                                            dim3(512), dim3(512), a2, 0, stream);
        if (e1 == hipSuccess && e2 == hipSuccess) done = true;
        else g_coop = 0;   // never try coop again this process
    }

    if (!done) {
        // -------- fallback: round-2 split pipeline (known good) --------
        FbPrep fp;
        for (int m = 0; m < 6; ++m) { fp.W[m] = pc.W[m]; fp.hi[m] = pc.hi[m]; }
        fp.xin = pc.xin;
        fp.xout = pc.xout;
        fp.n4 = pc.n4;
        fp.nxBlocks = (pc.n4 + 255) / 256;
        fp.dst = e_dst;
        fp.nE = nE;
        fp.bucketCnt = bucketCnt;

        int nChunk = pc.nChunk, nBk = pc.nBk;
        hipMemsetAsync(bucketCnt, 0, 512 * 4, stream);
        fb_prep<<<344 + fp.nxBlocks + nChunk, 256, 0, stream>>>(fp);
        bs_scan<<<1, 512, 0, stream>>>(bucketCnt, bucketBase, bucketCur, off, M, nE);
        bs_scatter<<<nChunk, 512, 0, stream>>>(e_src, e_dst, nE, bucketCur, ebuf);
        bs_build<<<nBk, 512, 0, stream>>>(ebuf, bucketBase, off, esrc, M);

        int gA = (M + 15) / 16;
        int nTP = (M + 255) / 256;
        // layer 0
        fb_aggr<<<gA, 256, 0, stream>>>((const uint4*)xb, off, esrc, Ls.eps0, (uint4*)Ahi, M);
        fb_mlp<8, false><<<nTP, 512, 0, stream>>>((const unsigned short*)Ahi, Ls.W1_0, Ls.B1_0,
                                                  Ls.W2_0, Ls.B2_0, Hb, nullptr, M);
        // layer 1
        fb_aggr<<<gA, 256, 0, stream>>>((const uint4*)Hb, off, esrc, Ls.eps1, (uint4*)Ahi, M);
        fb_mlp<8, false><<<nTP, 512, 0, stream>>>((const unsigned short*)Ahi, Ls.W1_1, Ls.B1_1,
                                                  Ls.W2_1, Ls.B2_1, xb, nullptr, M);
        // layer 2 (log_softmax fused)
        fb_aggr<<<gA, 256, 0, stream>>>((const uint4*)xb, off, esrc, Ls.eps2, (uint4*)Ahi, M);
        fb_mlp<3, true><<<nTP, 512, 0, stream>>>((const unsigned short*)Ahi, Ls.W1_2, Ls.B1_2,
                                                 Ls.W2_2, Ls.B2_2, nullptr, (float*)d_out, M);
    }
}

// Round 5
// 511.462 us; speedup vs baseline: 1.2306x; 1.2306x over previous
//
#include <hip/hip_runtime.h>
#include <stdint.h>

typedef __attribute__((ext_vector_type(8))) short short8;
typedef __attribute__((ext_vector_type(4))) short short4v;
typedef __attribute__((ext_vector_type(4))) float float4v;

__device__ __forceinline__ unsigned short f2bf(float f) {
    union { float f; unsigned int u; } c; c.f = f;
    unsigned int x = c.u;
    unsigned int r = x + 0x7fffu + ((x >> 16) & 1u);   // RNE
    return (unsigned short)(r >> 16);
}
__device__ __forceinline__ void unpack2(unsigned int u, float& lo, float& hi) {
    union { unsigned int uu; float ff; } a, b;
    a.uu = u << 16;          // low bf16
    b.uu = u & 0xffff0000u;  // high bf16
    lo = a.ff; hi = b.ff;
}
__device__ __forceinline__ void acc8(uint4 v, float* s) {
    float a, b;
    unpack2(v.x, a, b); s[0] += a; s[1] += b;
    unpack2(v.y, a, b); s[2] += a; s[3] += b;
    unpack2(v.z, a, b); s[4] += a; s[5] += b;
    unpack2(v.w, a, b); s[6] += a; s[7] += b;
}

// ======= aggregation: a = (1+eps)*h + sum_{j->i} h_j ; one node per 16-lane quarter =======
// Two-batch software pipeline: gathers for batch k+1 are issued BEFORE accumulating
// batch k (double-buffered va/vb), and esrc indices are prefetched one batch ahead.
// Keeps 16 rows (4KB) in flight per quarter instead of 8.
__global__ __launch_bounds__(256) void k_aggr(const uint4* __restrict__ Hin,
                                              const int* __restrict__ off,
                                              const int* __restrict__ esrc,
                                              const float* __restrict__ epsp,
                                              uint4* __restrict__ Ahi, int M) {
    int w = threadIdx.x >> 6, lane = threadIdx.x & 63;
    int li = lane & 15, q = lane >> 4;
    int node = blockIdx.x * 16 + w * 4 + q;
    if (node >= M) return;
    float ep = 1.0f + epsp[0];
    uint4 ow = Hin[node * 16 + li];
    float s[8] = {0.f, 0.f, 0.f, 0.f, 0.f, 0.f, 0.f, 0.f};
    int i0 = off[node], e = off[node + 1];
    int nb = (e - i0) >> 3;          // full 8-batches
    uint4 va[8], vb[8];
    int idc[8], idn[8];

    if (nb > 0) {
        // prologue: batch 0 gathers + batch 1 index prefetch
#pragma unroll
        for (int j = 0; j < 8; ++j) idc[j] = esrc[i0 + j];
#pragma unroll
        for (int j = 0; j < 8; ++j) va[j] = Hin[idc[j] * 16 + li];
        if (nb > 1) {
#pragma unroll
            for (int j = 0; j < 8; ++j) idn[j] = esrc[i0 + 8 + j];
        }
        int b = 1;
        while (b + 1 < nb) {
            // issue batch b (idn), prefetch idx b+1, then consume batch b-1
#pragma unroll
            for (int j = 0; j < 8; ++j) vb[j] = Hin[idn[j] * 16 + li];
#pragma unroll
            for (int j = 0; j < 8; ++j) idc[j] = esrc[i0 + (b + 1) * 8 + j];
#pragma unroll
            for (int j = 0; j < 8; ++j) acc8(va[j], s);
            // issue batch b+1 (idc), prefetch idx b+2, consume batch b
#pragma unroll
            for (int j = 0; j < 8; ++j) va[j] = Hin[idc[j] * 16 + li];
            if (b + 2 < nb) {
#pragma unroll
                for (int j = 0; j < 8; ++j) idn[j] = esrc[i0 + (b + 2) * 8 + j];
            }
#pragma unroll
            for (int j = 0; j < 8; ++j) acc8(vb[j], s);
            b += 2;
        }
        if (b < nb) {                 // one remaining full batch (indices in idn)
#pragma unroll
            for (int j = 0; j < 8; ++j) vb[j] = Hin[idn[j] * 16 + li];
#pragma unroll
            for (int j = 0; j < 8; ++j) acc8(va[j], s);
#pragma unroll
            for (int j = 0; j < 8; ++j) acc8(vb[j], s);
        } else {
#pragma unroll
            for (int j = 0; j < 8; ++j) acc8(va[j], s);
        }
    }
    // tail [i0 + nb*8, e): one predicated batch (clamped dup loads are L1 hits)
    int i = i0 + nb * 8;
    if (i < e) {
        int last = e - 1;
        uint4 v[8];
#pragma unroll
        for (int j = 0; j < 8; ++j) {
            int k = i + j;
            int cl = k < last ? k : last;
            v[j] = Hin[esrc[cl] * 16 + li];
        }
#pragma unroll
        for (int j = 0; j < 8; ++j) {
            bool ok = (i + j) < e;
            uint4 u2;
            u2.x = ok ? v[j].x : 0u;
            u2.y = ok ? v[j].y : 0u;
            u2.z = ok ? v[j].z : 0u;
            u2.w = ok ? v[j].w : 0u;
            acc8(u2, s);
        }
    }
    float o[8];
    unpack2(ow.x, o[0], o[1]);
    unpack2(ow.y, o[2], o[3]);
    unpack2(ow.z, o[4], o[5]);
    unpack2(ow.w, o[6], o[7]);
#pragma unroll
    for (int k = 0; k < 8; ++k) s[k] = ep * o[k] + s[k];
    uint4 r;
    r.x = ((unsigned int)f2bf(s[1]) << 16) | f2bf(s[0]);
    r.y = ((unsigned int)f2bf(s[3]) << 16) | f2bf(s[2]);
    r.z = ((unsigned int)f2bf(s[5]) << 16) | f2bf(s[4]);
    r.w = ((unsigned int)f2bf(s[7]) << 16) | f2bf(s[6]);
    Ahi[node * 16 + li] = r;
}

// ---- MLP: 512 threads; 256-row tile-pair per block iteration; LDS W1 -> W2 ----
template <int NT2, bool LOGITS>
__global__ __launch_bounds__(512, 4) void k_mlp(const unsigned short* __restrict__ AhiS,
                                                const unsigned short* __restrict__ W1h,
                                                const float* __restrict__ B1,
                                                const unsigned short* __restrict__ W2h,
                                                const float* __restrict__ B2,
                                                unsigned short* __restrict__ HOut,
                                                float* __restrict__ LOut, int M) {
    __shared__ short wbuf[128 * 136];
    int t = threadIdx.x, w = t >> 6, lane = t & 63;
    int lm = lane & 15, lg = lane >> 4;
    int h = w >> 2, wq = w & 3;
    int nTP = (M + 255) / 256;
    for (int tp = blockIdx.x; tp < nTP; tp += gridDim.x) {
        __syncthreads();               // wbuf reuse guard
        int rbase = tp * 256 + h * 128;

        short8 xf2[2][4];
        bool act[2];
#pragma unroll
        for (int t2 = 0; t2 < 2; ++t2) {
            int r0 = rbase + t2 * 64 + wq * 16;
            act[t2] = (r0 < M);            // wave-uniform (M % 16 == 0)
            if (act[t2]) {
                const short* Xp = (const short*)AhiS + (r0 + lm) * 128 + lg * 8;
#pragma unroll
                for (int kb = 0; kb < 4; ++kb) xf2[t2][kb] = *(const short8*)(Xp + kb * 32);
            } else {
#pragma unroll
                for (int kb = 0; kb < 4; ++kb) xf2[t2][kb] = (short8){0,0,0,0,0,0,0,0};
            }
        }
        constexpr int WTOT2 = NT2 * 16 * 128;               // shorts
        constexpr int W2CH = (WTOT2 + 4095) / 4096;         // 4 or 2
        short8 w1r[4], w2r[W2CH];
#pragma unroll
        for (int u = 0; u < 4; ++u) w1r[u] = *(const short8*)(W1h + t * 8 + u * 4096);
#pragma unroll
        for (int u = 0; u < W2CH; ++u) {
            int i = t * 8 + u * 4096;
            if (i < WTOT2) w2r[u] = *(const short8*)(W2h + i);
        }

        // stage W1
#pragma unroll
        for (int u = 0; u < 4; ++u) {
            int i = t * 8 + u * 4096;
            *(short8*)&wbuf[(i >> 7) * 136 + (i & 127)] = w1r[u];
        }
        __syncthreads();

        // GEMM1 (a = W1 frag, b = node frag -> D = H^T), pack H in registers
        short4v h2[2][8];
#pragma unroll
        for (int t2 = 0; t2 < 2; ++t2) {
            float4v acc1[8];
#pragma unroll
            for (int nt = 0; nt < 8; ++nt) acc1[nt] = (float4v){0.f, 0.f, 0.f, 0.f};
#pragma unroll
            for (int nt = 0; nt < 8; ++nt) {
#pragma unroll
                for (int kb = 0; kb < 4; ++kb) {
                    short8 wf = *(const short8*)&wbuf[(nt * 16 + lm) * 136 + kb * 32 + lg * 8];
                    acc1[nt] = __builtin_amdgcn_mfma_f32_16x16x32_bf16(wf, xf2[t2][kb], acc1[nt], 0, 0, 0);
                }
            }
#pragma unroll
            for (int nt = 0; nt < 8; ++nt) {
                float4 b1 = *(const float4*)(B1 + nt * 16 + lg * 4);
                float v0 = acc1[nt][0] + b1.x; v0 = v0 > 0.f ? v0 : 0.f;
                float v1 = acc1[nt][1] + b1.y; v1 = v1 > 0.f ? v1 : 0.f;
                float v2 = acc1[nt][2] + b1.z; v2 = v2 > 0.f ? v2 : 0.f;
                float v3 = acc1[nt][3] + b1.w; v3 = v3 > 0.f ? v3 : 0.f;
                h2[t2][nt] = (short4v){(short)f2bf(v0), (short)f2bf(v1),
                                       (short)f2bf(v2), (short)f2bf(v3)};
            }
        }

        __syncthreads();
        // stage W2
#pragma unroll
        for (int u = 0; u < W2CH; ++u) {
            int i = t * 8 + u * 4096;
            if (i < WTOT2) *(short8*)&wbuf[(i >> 7) * 136 + (i & 127)] = w2r[u];
        }
        __syncthreads();

        // GEMM2: K=16 MFMAs consume h2 directly
        float4v acc2[2][NT2];
#pragma unroll
        for (int t2 = 0; t2 < 2; ++t2)
#pragma unroll
            for (int ot = 0; ot < NT2; ++ot) acc2[t2][ot] = (float4v){0.f, 0.f, 0.f, 0.f};
#pragma unroll
        for (int ot = 0; ot < NT2; ++ot) {
#pragma unroll
            for (int nt = 0; nt < 8; ++nt) {
                short4v wf = *(const short4v*)&wbuf[(ot * 16 + lm) * 136 + nt * 16 + lg * 4];
#pragma unroll
                for (int t2 = 0; t2 < 2; ++t2)
                    acc2[t2][ot] = __builtin_amdgcn_mfma_f32_16x16x16bf16_1k(wf, h2[t2][nt],
                                                                             acc2[t2][ot], 0, 0, 0);
            }
        }

        // epilogue
#pragma unroll
        for (int t2 = 0; t2 < 2; ++t2) {
            if (!act[t2]) continue;
            int row = rbase + t2 * 64 + wq * 16 + lm;
            if (!LOGITS) {
#pragma unroll
                for (int ot = 0; ot < NT2; ++ot) {
                    float4 b2 = *(const float4*)(B2 + ot * 16 + lg * 4);
                    float v0 = acc2[t2][ot][0] + b2.x; v0 = v0 > 0.f ? v0 : 0.f;
                    float v1 = acc2[t2][ot][1] + b2.y; v1 = v1 > 0.f ? v1 : 0.f;
                    float v2 = acc2[t2][ot][2] + b2.z; v2 = v2 > 0.f ? v2 : 0.f;
                    float v3 = acc2[t2][ot][3] + b2.w; v3 = v3 > 0.f ? v3 : 0.f;
                    uint2 pk;
                    pk.x = ((unsigned int)f2bf(v1) << 16) | f2bf(v0);
                    pk.y = ((unsigned int)f2bf(v3) << 16) | f2bf(v2);
                    *(uint2*)(HOut + row * 128 + ot * 16 + lg * 4) = pk;
                }
            } else {
                float vv[NT2][4];
#pragma unroll
                for (int ot = 0; ot < NT2; ++ot) {
                    int ub = ot * 16 + lg * 4;
                    bool valid = ub <= 36;
                    float4 b2 = valid ? *(const float4*)(B2 + ub) : (float4){0.f, 0.f, 0.f, 0.f};
                    vv[ot][0] = valid ? acc2[t2][ot][0] + b2.x : -1e30f;
                    vv[ot][1] = valid ? acc2[t2][ot][1] + b2.y : -1e30f;
                    vv[ot][2] = valid ? acc2[t2][ot][2] + b2.z : -1e30f;
                    vv[ot][3] = valid ? acc2[t2][ot][3] + b2.w : -1e30f;
                }
                float m = -1e30f;
#pragma unroll
                for (int ot = 0; ot < NT2; ++ot)
#pragma unroll
                    for (int r = 0; r < 4; ++r) m = fmaxf(m, vv[ot][r]);
                m = fmaxf(m, __shfl_xor(m, 16, 64));
                m = fmaxf(m, __shfl_xor(m, 32, 64));
                float s = 0.f;
#pragma unroll
                for (int ot = 0; ot < NT2; ++ot)
#pragma unroll
                    for (int r = 0; r < 4; ++r)
                        s += (vv[ot][r] > -1e29f) ? expf(vv[ot][r] - m) : 0.f;
                s += __shfl_xor(s, 16, 64);
                s += __shfl_xor(s, 32, 64);
                float ls = m + logf(s);
#pragma unroll
                for (int ot = 0; ot < NT2; ++ot) {
                    int ub = ot * 16 + lg * 4;
                    if (ub <= 36) {
                        float4 outv = {vv[ot][0] - ls, vv[ot][1] - ls,
                                       vv[ot][2] - ls, vv[ot][3] - ls};
                        *(float4*)(LOut + row * 40 + ub) = outv;
                    }
                }
            }
        }
    }
}

// ==== combined prep: weights fp32 W[k][n] -> bf16 [n][k]; x -> bf16; edge histogram ====
struct Prep {
    const float* W[6];
    unsigned short* hi[6];
    const float4* xin;
    uint2* xout;
    int n4;
    int nxBlocks;
    const int* dst;
    int nE;
    int* bucketCnt;
};

__global__ __launch_bounds__(256) void k_prep(Prep p) {
    __shared__ int c[512];
    int b = blockIdx.x;
    int t = threadIdx.x;
    if (b < 344) {
        int mat = b >> 6;     // mats 0..4: 64 blocks each; mat 5: blocks 320..343
        int rel = b - mat * 64;
        int NPAD = (mat == 5) ? 48 : 128;
        int N = (mat == 5) ? 40 : 128;
        int idx = rel * 256 + t;
        if (idx >= NPAD * 128) return;
        int n = idx >> 7, k = idx & 127;
        float w = (n < N) ? p.W[mat][k * N + n] : 0.f;
        p.hi[mat][idx] = f2bf(w);
    } else if (b < 344 + p.nxBlocks) {
        int i = (b - 344) * 256 + t;
        if (i >= p.n4) return;
        float4 v = p.xin[i];
        uint2 o;
        o.x = ((unsigned int)f2bf(v.y) << 16) | f2bf(v.x);
        o.y = ((unsigned int)f2bf(v.w) << 16) | f2bf(v.z);
        p.xout[i] = o;
    } else {
        // edge histogram (bucket = dst>>8); bucketCnt pre-zeroed by memset
        for (int i = t; i < 512; i += 256) c[i] = 0;
        __syncthreads();
        int base = (b - 344 - p.nxBlocks) * 4096;
        for (int i = t; i < 4096; i += 256) {
            int e = base + i;
            if (e < p.nE) atomicAdd(&c[p.dst[e] >> 8], 1);
        }
        __syncthreads();
        for (int i = t; i < 512; i += 256)
            if (c[i]) atomicAdd(&p.bucketCnt[i], c[i]);
    }
}

__global__ __launch_bounds__(512) void bs_scan(const int* __restrict__ bucketCnt,
                                               int* __restrict__ bucketBase,
                                               int* __restrict__ bucketCur,
                                               int* __restrict__ off, int M, int nE) {
    __shared__ int s[512];
    int t = threadIdx.x;
    int v = bucketCnt[t];
    s[t] = v;
    __syncthreads();
    for (int o = 1; o < 512; o <<= 1) {
        int x = (t >= o) ? s[t - o] : 0;
        __syncthreads();
        s[t] += x;
        __syncthreads();
    }
    bucketBase[t] = s[t] - v;
    bucketCur[t] = s[t] - v;
    if (t == 511) bucketBase[512] = s[511];
    if (t == 0) off[M] = nE;
}

// packed entry: src (bits 0..16) | (dst&255)<<17
__global__ __launch_bounds__(512) void bs_scatter(const int* __restrict__ src,
                                                  const int* __restrict__ dst, int nE,
                                                  int* __restrict__ bucketCur,
                                                  unsigned int* __restrict__ ebuf) {
    __shared__ int cnt[512];
    __shared__ int excl[512];
    __shared__ int chunk[512];
    __shared__ unsigned int buf[4096];
    __shared__ unsigned short bkt[4096];
    int t = threadIdx.x;
    cnt[t] = 0;
    __syncthreads();
    int base = blockIdx.x * 4096;
    int n = nE - base; if (n > 4096) n = 4096;
    unsigned int pk[8]; int bk[8]; int rk[8];
#pragma unroll
    for (int u = 0; u < 8; ++u) {
        int i = t + u * 512;
        if (i < n) {
            int e = base + i;
            int d = dst[e];
            int b = d >> 8;
            bk[u] = b;
            pk[u] = (unsigned int)src[e] | ((unsigned int)(d & 255) << 17);
            rk[u] = atomicAdd(&cnt[b], 1);
        } else bk[u] = -1;
    }
    __syncthreads();
    excl[t] = cnt[t];
    __syncthreads();
    for (int o = 1; o < 512; o <<= 1) {
        int x = (t >= o) ? excl[t - o] : 0;
        __syncthreads();
        excl[t] += x;
        __syncthreads();
    }
    int ex = excl[t] - cnt[t];
    __syncthreads();
    excl[t] = ex;
    if (cnt[t]) chunk[t] = atomicAdd(&bucketCur[t], cnt[t]);
    __syncthreads();
#pragma unroll
    for (int u = 0; u < 8; ++u) {
        if (bk[u] >= 0) {
            int lp = excl[bk[u]] + rk[u];
            buf[lp] = pk[u];
            bkt[lp] = (unsigned short)bk[u];
        }
    }
    __syncthreads();
    for (int i = t; i < n; i += 512) {
        int b = bkt[i];
        ebuf[chunk[b] + (i - excl[b])] = buf[i];
    }
}

__global__ __launch_bounds__(512) void bs_build(const unsigned int* __restrict__ ebuf,
                                                const int* __restrict__ bucketBase,
                                                int* __restrict__ off,
                                                int* __restrict__ esrc, int M) {
    __shared__ int cnt[256];
    __shared__ int excl[256];
    __shared__ int obuf[5120];
    int t = threadIdx.x, b = blockIdx.x;
    int base = bucketBase[b];
    int n = bucketBase[b + 1] - base;
    if (t < 256) cnt[t] = 0;
    __syncthreads();
    unsigned int pk[10]; int dl[10]; int rk[10];
#pragma unroll
    for (int u = 0; u < 10; ++u) {
        int i = t + u * 512;
        if (i < n) {
            unsigned int p = ebuf[base + i];
            pk[u] = p;
            int d = (p >> 17) & 255;
            dl[u] = d;
            rk[u] = atomicAdd(&cnt[d], 1);
        } else dl[u] = -1;
    }
    __syncthreads();
    if (t < 256) excl[t] = cnt[t];
    __syncthreads();
    for (int o = 1; o < 256; o <<= 1) {
        int x = (t < 256 && t >= o) ? excl[t - o] : 0;
        __syncthreads();
        if (t < 256) excl[t] += x;
        __syncthreads();
    }
    if (t < 256) {
        int ex = excl[t] - cnt[t];
        int node = b * 256 + t;
        if (node < M) off[node] = base + ex;
        excl[t] = ex;
    }
    __syncthreads();
#pragma unroll
    for (int u = 0; u < 10; ++u) {
        if (dl[u] >= 0) {
            int lp = excl[dl[u]] + rk[u];
            if (lp < 5120) obuf[lp] = (int)(pk[u] & 0x1FFFF);
        }
    }
    __syncthreads();
    for (int i = t; i < n; i += 512) esrc[base + i] = obuf[i];
}

// ---------------- launch ----------------
extern "C" void kernel_launch(void* const* d_in, const int* in_sizes, int n_in,
                              void* d_out, int out_size, void* d_ws, size_t ws_size,
                              hipStream_t stream) {
    const float* x    = (const float*)d_in[0];
    const int*   edges = (const int*)d_in[1];
    const float* eps0 = (const float*)d_in[6];
    const float* eps1 = (const float*)d_in[11];
    const float* eps2 = (const float*)d_in[16];
    const float* B1[3] = {(const float*)d_in[3], (const float*)d_in[8], (const float*)d_in[13]};
    const float* B2[3] = {(const float*)d_in[5], (const float*)d_in[10], (const float*)d_in[15]};

    int M  = in_sizes[0] / 128;   // 100000
    int nE = in_sizes[1] / 2;     // 1600000
    const int* e_src = edges;
    const int* e_dst = edges + nE;

    char* ws = (char*)d_ws;
    size_t o = 0;
    auto alloc = [&](size_t bytes) {
        size_t p = o;
        o = (o + bytes + 511) & ~(size_t)511;
        return ws + p;
    };
    int* bucketCnt  = (int*)alloc(512 * 4);
    int* bucketBase = (int*)alloc(513 * 4);
    int* bucketCur  = (int*)alloc(512 * 4);
    int* off  = (int*)alloc((size_t)(M + 1) * 4);
    int* esrc = (int*)alloc((size_t)nE * 4);
    unsigned int* ebuf = (unsigned int*)alloc((size_t)nE * 4);

    Prep pp;
    pp.W[0] = (const float*)d_in[2];  pp.W[1] = (const float*)d_in[4];
    pp.W[2] = (const float*)d_in[7];  pp.W[3] = (const float*)d_in[9];
    pp.W[4] = (const float*)d_in[12]; pp.W[5] = (const float*)d_in[14];
    for (int m = 0; m < 6; ++m) {
        int npad = (m == 5) ? 48 : 128;
        pp.hi[m] = (unsigned short*)alloc((size_t)npad * 128 * 2);
    }
    unsigned short* xb  = (unsigned short*)alloc((size_t)M * 128 * 2);
    unsigned short* Ahi = (unsigned short*)alloc((size_t)M * 128 * 2);
    unsigned short* Hb  = (unsigned short*)alloc((size_t)M * 128 * 2);
    pp.xin = (const float4*)x;
    pp.xout = (uint2*)xb;
    pp.n4 = M * 32;
    pp.nxBlocks = (pp.n4 + 255) / 256;
    pp.dst = e_dst;
    pp.nE = nE;
    pp.bucketCnt = bucketCnt;
    (void)ws_size; (void)n_in; (void)out_size;

    int nChunk = (nE + 4095) / 4096;
    int nBk = (M + 255) / 256;

    hipMemsetAsync(bucketCnt, 0, 512 * 4, stream);
    k_prep<<<344 + pp.nxBlocks + nChunk, 256, 0, stream>>>(pp);
    bs_scan<<<1, 512, 0, stream>>>(bucketCnt, bucketBase, bucketCur, off, M, nE);
    bs_scatter<<<nChunk, 512, 0, stream>>>(e_src, e_dst, nE, bucketCur, ebuf);
    bs_build<<<nBk, 512, 0, stream>>>(ebuf, bucketBase, off, esrc, M);

    int gA = (M + 15) / 16;      // 6250
    int nTP = (M + 255) / 256;   // 391

    // layer 0
    k_aggr<<<gA, 256, 0, stream>>>((const uint4*)xb, off, esrc, eps0, (uint4*)Ahi, M);
    k_mlp<8, false><<<nTP, 512, 0, stream>>>(Ahi, pp.hi[0], B1[0],
                                             pp.hi[1], B2[0], Hb, nullptr, M);
    // layer 1
    k_aggr<<<gA, 256, 0, stream>>>((const uint4*)Hb, off, esrc, eps1, (uint4*)Ahi, M);
    k_mlp<8, false><<<nTP, 512, 0, stream>>>(Ahi, pp.hi[2], B1[1],
                                             pp.hi[3], B2[1], Hb, nullptr, M);
    // layer 2 (log_softmax fused)
    k_aggr<<<gA, 256, 0, stream>>>((const uint4*)Hb, off, esrc, eps2, (uint4*)Ahi, M);
    k_mlp<3, true><<<nTP, 512, 0, stream>>>(Ahi, pp.hi[4], B1[2],
                                            pp.hi[5], B2[2], nullptr,
                                            (float*)d_out, M);
}

// Round 6
// 413.300 us; speedup vs baseline: 1.5229x; 1.2375x over previous
//
#include <hip/hip_runtime.h>
#include <stdint.h>

typedef __attribute__((ext_vector_type(8))) short short8;
typedef __attribute__((ext_vector_type(4))) short short4v;
typedef __attribute__((ext_vector_type(4))) float float4v;

__device__ __forceinline__ unsigned short f2bf(float f) {
    union { float f; unsigned int u; } c; c.f = f;
    unsigned int x = c.u;
    unsigned int r = x + 0x7fffu + ((x >> 16) & 1u);   // RNE
    return (unsigned short)(r >> 16);
}
__device__ __forceinline__ void unpack2(unsigned int u, float& lo, float& hi) {
    union { unsigned int uu; float ff; } a, b;
    a.uu = u << 16;          // low bf16
    b.uu = u & 0xffff0000u;  // high bf16
    lo = a.ff; hi = b.ff;
}
__device__ __forceinline__ void acc8(uint4 v, float* s) {
    float a, b;
    unpack2(v.x, a, b); s[0] += a; s[1] += b;
    unpack2(v.y, a, b); s[2] += a; s[3] += b;
    unpack2(v.z, a, b); s[4] += a; s[5] += b;
    unpack2(v.w, a, b); s[6] += a; s[7] += b;
}

// ======= aggregation: a = (1+eps)*h + sum_{j->i} h_j ; one node per 16-lane quarter =======
// Two-batch software pipeline (verified -5.5us/dispatch in round 5): gathers for
// batch k+1 issue BEFORE accumulating batch k; esrc indices prefetched a batch ahead.
__global__ __launch_bounds__(256) void k_aggr(const uint4* __restrict__ Hin,
                                              const int* __restrict__ off,
                                              const int* __restrict__ esrc,
                                              const float* __restrict__ epsp,
                                              uint4* __restrict__ Ahi, int M) {
    int w = threadIdx.x >> 6, lane = threadIdx.x & 63;
    int li = lane & 15, q = lane >> 4;
    int node = blockIdx.x * 16 + w * 4 + q;
    if (node >= M) return;
    float ep = 1.0f + epsp[0];
    uint4 ow = Hin[node * 16 + li];
    float s[8] = {0.f, 0.f, 0.f, 0.f, 0.f, 0.f, 0.f, 0.f};
    int i0 = off[node], e = off[node + 1];
    int nb = (e - i0) >> 3;          // full 8-batches
    uint4 va[8], vb[8];
    int idc[8], idn[8];

    if (nb > 0) {
#pragma unroll
        for (int j = 0; j < 8; ++j) idc[j] = esrc[i0 + j];
#pragma unroll
        for (int j = 0; j < 8; ++j) va[j] = Hin[idc[j] * 16 + li];
        if (nb > 1) {
#pragma unroll
            for (int j = 0; j < 8; ++j) idn[j] = esrc[i0 + 8 + j];
        }
        int b = 1;
        while (b + 1 < nb) {
#pragma unroll
            for (int j = 0; j < 8; ++j) vb[j] = Hin[idn[j] * 16 + li];
#pragma unroll
            for (int j = 0; j < 8; ++j) idc[j] = esrc[i0 + (b + 1) * 8 + j];
#pragma unroll
            for (int j = 0; j < 8; ++j) acc8(va[j], s);
#pragma unroll
            for (int j = 0; j < 8; ++j) va[j] = Hin[idc[j] * 16 + li];
            if (b + 2 < nb) {
#pragma unroll
                for (int j = 0; j < 8; ++j) idn[j] = esrc[i0 + (b + 2) * 8 + j];
            }
#pragma unroll
            for (int j = 0; j < 8; ++j) acc8(vb[j], s);
            b += 2;
        }
        if (b < nb) {                 // one remaining full batch (indices in idn)
#pragma unroll
            for (int j = 0; j < 8; ++j) vb[j] = Hin[idn[j] * 16 + li];
#pragma unroll
            for (int j = 0; j < 8; ++j) acc8(va[j], s);
#pragma unroll
            for (int j = 0; j < 8; ++j) acc8(vb[j], s);
        } else {
#pragma unroll
            for (int j = 0; j < 8; ++j) acc8(va[j], s);
        }
    }
    // tail [i0 + nb*8, e): one predicated batch (clamped dup loads are L1 hits)
    int i = i0 + nb * 8;
    if (i < e) {
        int last = e - 1;
        uint4 v[8];
#pragma unroll
        for (int j = 0; j < 8; ++j) {
            int k = i + j;
            int cl = k < last ? k : last;
            v[j] = Hin[esrc[cl] * 16 + li];
        }
#pragma unroll
        for (int j = 0; j < 8; ++j) {
            bool ok = (i + j) < e;
            uint4 u2;
            u2.x = ok ? v[j].x : 0u;
            u2.y = ok ? v[j].y : 0u;
            u2.z = ok ? v[j].z : 0u;
            u2.w = ok ? v[j].w : 0u;
            acc8(u2, s);
        }
    }
    float o[8];
    unpack2(ow.x, o[0], o[1]);
    unpack2(ow.y, o[2], o[3]);
    unpack2(ow.z, o[4], o[5]);
    unpack2(ow.w, o[6], o[7]);
#pragma unroll
    for (int k = 0; k < 8; ++k) s[k] = ep * o[k] + s[k];
    uint4 r;
    r.x = ((unsigned int)f2bf(s[1]) << 16) | f2bf(s[0]);
    r.y = ((unsigned int)f2bf(s[3]) << 16) | f2bf(s[2]);
    r.z = ((unsigned int)f2bf(s[5]) << 16) | f2bf(s[4]);
    r.w = ((unsigned int)f2bf(s[7]) << 16) | f2bf(s[6]);
    Ahi[node * 16 + li] = r;
}

// ============ fused 2-layer MLP: 256 threads, 128-row tile, 782 co-resident blocks ============
// (256,3): 3 blocks/CU. Reverted from 512-thread/(512,4): 391 one-tile blocks gave only
// 1.5 blocks/CU with no overlap of phase bubbles -> 67us vs 27us (round-5 lesson).
template <int NT2, bool LOGITS>
__global__ __launch_bounds__(256, 3) void k_mlp(const unsigned short* __restrict__ AhiS,
                                                const unsigned short* __restrict__ W1h,
                                                const float* __restrict__ B1,
                                                const unsigned short* __restrict__ W2h,
                                                const float* __restrict__ B2,
                                                unsigned short* __restrict__ HOut,
                                                float* __restrict__ LOut, int M) {
    __shared__ short wbuf[128 * 136];     // 272 B row stride
    int t = threadIdx.x, w = t >> 6, lane = t & 63;
    int lm = lane & 15, lg = lane >> 4;
    int rbase = blockIdx.x * 128;

    // ---- prefetch: A fragments (both halves), W1 + W2 staging words ----
    short8 xf2[2][4];
    bool act[2];
#pragma unroll
    for (int t2 = 0; t2 < 2; ++t2) {
        int r0 = rbase + t2 * 64 + w * 16;
        act[t2] = (r0 < M);                   // wave-uniform (M % 16 == 0)
        if (act[t2]) {
            const short* Xp = (const short*)AhiS + (r0 + lm) * 128 + lg * 8;
#pragma unroll
            for (int kb = 0; kb < 4; ++kb) xf2[t2][kb] = *(const short8*)(Xp + kb * 32);
        } else {
#pragma unroll
            for (int kb = 0; kb < 4; ++kb) xf2[t2][kb] = (short8){0,0,0,0,0,0,0,0};
        }
    }
    constexpr int W2CH = (NT2 * 16 * 128) / 2048;   // 8 or 3
    short8 w1r[8], w2r[W2CH];
#pragma unroll
    for (int u = 0; u < 8; ++u) w1r[u] = *(const short8*)(W1h + t * 8 + u * 2048);
#pragma unroll
    for (int u = 0; u < W2CH; ++u) w2r[u] = *(const short8*)(W2h + t * 8 + u * 2048);

    // ---- stage W1 ----
#pragma unroll
    for (int u = 0; u < 8; ++u) {
        int i = t * 8 + u * 2048;
        *(short8*)&wbuf[(i >> 7) * 136 + (i & 127)] = w1r[u];
    }
    __syncthreads();

    // ---- GEMM1 (a = W1 frag, b = node frag  ->  D = H^T), pack H in registers ----
    short4v h2[2][8];
#pragma unroll
    for (int t2 = 0; t2 < 2; ++t2) {
        float4v acc1[8];
#pragma unroll
        for (int nt = 0; nt < 8; ++nt) acc1[nt] = (float4v){0.f, 0.f, 0.f, 0.f};
#pragma unroll
        for (int nt = 0; nt < 8; ++nt) {
#pragma unroll
            for (int kb = 0; kb < 4; ++kb) {
                short8 wf = *(const short8*)&wbuf[(nt * 16 + lm) * 136 + kb * 32 + lg * 8];
                acc1[nt] = __builtin_amdgcn_mfma_f32_16x16x32_bf16(wf, xf2[t2][kb], acc1[nt], 0, 0, 0);
            }
        }
#pragma unroll
        for (int nt = 0; nt < 8; ++nt) {
            float4 b1 = *(const float4*)(B1 + nt * 16 + lg * 4);
            float v0 = acc1[nt][0] + b1.x; v0 = v0 > 0.f ? v0 : 0.f;
            float v1 = acc1[nt][1] + b1.y; v1 = v1 > 0.f ? v1 : 0.f;
            float v2 = acc1[nt][2] + b1.z; v2 = v2 > 0.f ? v2 : 0.f;
            float v3 = acc1[nt][3] + b1.w; v3 = v3 > 0.f ? v3 : 0.f;
            h2[t2][nt] = (short4v){(short)f2bf(v0), (short)f2bf(v1),
                                   (short)f2bf(v2), (short)f2bf(v3)};
        }
    }

    __syncthreads();
    // ---- stage W2 (from prefetched registers) ----
#pragma unroll
    for (int u = 0; u < W2CH; ++u) {
        int i = t * 8 + u * 2048;
        *(short8*)&wbuf[(i >> 7) * 136 + (i & 127)] = w2r[u];
    }
    __syncthreads();

    // ---- GEMM2: K=16 MFMAs consume h2 directly (B-operand layout match) ----
    float4v acc2[2][NT2];
#pragma unroll
    for (int t2 = 0; t2 < 2; ++t2)
#pragma unroll
        for (int ot = 0; ot < NT2; ++ot) acc2[t2][ot] = (float4v){0.f, 0.f, 0.f, 0.f};
#pragma unroll
    for (int ot = 0; ot < NT2; ++ot) {
#pragma unroll
        for (int nt = 0; nt < 8; ++nt) {
            short4v wf = *(const short4v*)&wbuf[(ot * 16 + lm) * 136 + nt * 16 + lg * 4];
#pragma unroll
            for (int t2 = 0; t2 < 2; ++t2)
                acc2[t2][ot] = __builtin_amdgcn_mfma_f32_16x16x16bf16_1k(wf, h2[t2][nt],
                                                                         acc2[t2][ot], 0, 0, 0);
        }
    }

    // ---- epilogue: lane owns node (r0+lm), hidden units ot*16+lg*4+{0..3} ----
#pragma unroll
    for (int t2 = 0; t2 < 2; ++t2) {
        if (!act[t2]) continue;
        int row = rbase + t2 * 64 + w * 16 + lm;
        if (!LOGITS) {
#pragma unroll
            for (int ot = 0; ot < NT2; ++ot) {
                float4 b2 = *(const float4*)(B2 + ot * 16 + lg * 4);
                float v0 = acc2[t2][ot][0] + b2.x; v0 = v0 > 0.f ? v0 : 0.f;
                float v1 = acc2[t2][ot][1] + b2.y; v1 = v1 > 0.f ? v1 : 0.f;
                float v2 = acc2[t2][ot][2] + b2.z; v2 = v2 > 0.f ? v2 : 0.f;
                float v3 = acc2[t2][ot][3] + b2.w; v3 = v3 > 0.f ? v3 : 0.f;
                uint2 pk;
                pk.x = ((unsigned int)f2bf(v1) << 16) | f2bf(v0);
                pk.y = ((unsigned int)f2bf(v3) << 16) | f2bf(v2);
                *(uint2*)(HOut + row * 128 + ot * 16 + lg * 4) = pk;
            }
        } else {
            float vv[NT2][4];
#pragma unroll
            for (int ot = 0; ot < NT2; ++ot) {
                int ub = ot * 16 + lg * 4;
                bool valid = ub <= 36;
                float4 b2 = valid ? *(const float4*)(B2 + ub) : (float4){0.f, 0.f, 0.f, 0.f};
                vv[ot][0] = valid ? acc2[t2][ot][0] + b2.x : -1e30f;
                vv[ot][1] = valid ? acc2[t2][ot][1] + b2.y : -1e30f;
                vv[ot][2] = valid ? acc2[t2][ot][2] + b2.z : -1e30f;
                vv[ot][3] = valid ? acc2[t2][ot][3] + b2.w : -1e30f;
            }
            float m = -1e30f;
#pragma unroll
            for (int ot = 0; ot < NT2; ++ot)
#pragma unroll
                for (int r = 0; r < 4; ++r) m = fmaxf(m, vv[ot][r]);
            m = fmaxf(m, __shfl_xor(m, 16, 64));
            m = fmaxf(m, __shfl_xor(m, 32, 64));
            float s = 0.f;
#pragma unroll
            for (int ot = 0; ot < NT2; ++ot)
#pragma unroll
                for (int r = 0; r < 4; ++r)
                    s += (vv[ot][r] > -1e29f) ? expf(vv[ot][r] - m) : 0.f;
            s += __shfl_xor(s, 16, 64);
            s += __shfl_xor(s, 32, 64);
            float ls = m + logf(s);
#pragma unroll
            for (int ot = 0; ot < NT2; ++ot) {
                int ub = ot * 16 + lg * 4;
                if (ub <= 36) {
                    float4 outv = {vv[ot][0] - ls, vv[ot][1] - ls,
                                   vv[ot][2] - ls, vv[ot][3] - ls};
                    *(float4*)(LOut + row * 40 + ub) = outv;
                }
            }
        }
    }
}

// ==== combined prep: weights fp32 W[k][n] -> bf16 [n][k]; x -> bf16; edge histogram ====
struct Prep {
    const float* W[6];
    unsigned short* hi[6];
    const float4* xin;
    uint2* xout;
    int n4;
    int nxBlocks;
    const int* dst;
    int nE;
    int* bucketCnt;
};

__global__ __launch_bounds__(256) void k_prep(Prep p) {
    __shared__ int c[512];
    int b = blockIdx.x;
    int t = threadIdx.x;
    if (b < 344) {
        int mat = b >> 6;     // mats 0..4: 64 blocks each; mat 5: blocks 320..343
        int rel = b - mat * 64;
        int NPAD = (mat == 5) ? 48 : 128;
        int N = (mat == 5) ? 40 : 128;
        int idx = rel * 256 + t;
        if (idx >= NPAD * 128) return;
        int n = idx >> 7, k = idx & 127;
        float w = (n < N) ? p.W[mat][k * N + n] : 0.f;
        p.hi[mat][idx] = f2bf(w);
    } else if (b < 344 + p.nxBlocks) {
        int i = (b - 344) * 256 + t;
        if (i >= p.n4) return;
        float4 v = p.xin[i];
        uint2 o;
        o.x = ((unsigned int)f2bf(v.y) << 16) | f2bf(v.x);
        o.y = ((unsigned int)f2bf(v.w) << 16) | f2bf(v.z);
        p.xout[i] = o;
    } else {
        // edge histogram (bucket = dst>>8); bucketCnt pre-zeroed by memset
        for (int i = t; i < 512; i += 256) c[i] = 0;
        __syncthreads();
        int base = (b - 344 - p.nxBlocks) * 4096;
        for (int i = t; i < 4096; i += 256) {
            int e = base + i;
            if (e < p.nE) atomicAdd(&c[p.dst[e] >> 8], 1);
        }
        __syncthreads();
        for (int i = t; i < 512; i += 256)
            if (c[i]) atomicAdd(&p.bucketCnt[i], c[i]);
    }
}

__global__ __launch_bounds__(512) void bs_scan(const int* __restrict__ bucketCnt,
                                               int* __restrict__ bucketBase,
                                               int* __restrict__ bucketCur,
                                               int* __restrict__ off, int M, int nE) {
    __shared__ int s[512];
    int t = threadIdx.x;
    int v = bucketCnt[t];
    s[t] = v;
    __syncthreads();
    for (int o = 1; o < 512; o <<= 1) {
        int x = (t >= o) ? s[t - o] : 0;
        __syncthreads();
        s[t] += x;
        __syncthreads();
    }
    bucketBase[t] = s[t] - v;
    bucketCur[t] = s[t] - v;
    if (t == 511) bucketBase[512] = s[511];
    if (t == 0) off[M] = nE;
}

// packed entry: src (bits 0..16) | (dst&255)<<17
__global__ __launch_bounds__(512) void bs_scatter(const int* __restrict__ src,
                                                  const int* __restrict__ dst, int nE,
                                                  int* __restrict__ bucketCur,
                                                  unsigned int* __restrict__ ebuf) {
    __shared__ int cnt[512];
    __shared__ int excl[512];
    __shared__ int chunk[512];
    __shared__ unsigned int buf[4096];
    __shared__ unsigned short bkt[4096];
    int t = threadIdx.x;
    cnt[t] = 0;
    __syncthreads();
    int base = blockIdx.x * 4096;
    int n = nE - base; if (n > 4096) n = 4096;
    unsigned int pk[8]; int bk[8]; int rk[8];
#pragma unroll
    for (int u = 0; u < 8; ++u) {
        int i = t + u * 512;
        if (i < n) {
            int e = base + i;
            int d = dst[e];
            int b = d >> 8;
            bk[u] = b;
            pk[u] = (unsigned int)src[e] | ((unsigned int)(d & 255) << 17);
            rk[u] = atomicAdd(&cnt[b], 1);
        } else bk[u] = -1;
    }
    __syncthreads();
    excl[t] = cnt[t];
    __syncthreads();
    for (int o = 1; o < 512; o <<= 1) {
        int x = (t >= o) ? excl[t - o] : 0;
        __syncthreads();
        excl[t] += x;
        __syncthreads();
    }
    int ex = excl[t] - cnt[t];
    __syncthreads();
    excl[t] = ex;
    if (cnt[t]) chunk[t] = atomicAdd(&bucketCur[t], cnt[t]);
    __syncthreads();
#pragma unroll
    for (int u = 0; u < 8; ++u) {
        if (bk[u] >= 0) {
            int lp = excl[bk[u]] + rk[u];
            buf[lp] = pk[u];
            bkt[lp] = (unsigned short)bk[u];
        }
    }
    __syncthreads();
    for (int i = t; i < n; i += 512) {
        int b = bkt[i];
        ebuf[chunk[b] + (i - excl[b])] = buf[i];
    }
}

__global__ __launch_bounds__(512) void bs_build(const unsigned int* __restrict__ ebuf,
                                                const int* __restrict__ bucketBase,
                                                int* __restrict__ off,
                                                int* __restrict__ esrc, int M) {
    __shared__ int cnt[256];
    __shared__ int excl[256];
    __shared__ int obuf[5120];
    int t = threadIdx.x, b = blockIdx.x;
    int base = bucketBase[b];
    int n = bucketBase[b + 1] - base;
    if (t < 256) cnt[t] = 0;
    __syncthreads();
    unsigned int pk[10]; int dl[10]; int rk[10];
#pragma unroll
    for (int u = 0; u < 10; ++u) {
        int i = t + u * 512;
        if (i < n) {
            unsigned int p = ebuf[base + i];
            pk[u] = p;
            int d = (p >> 17) & 255;
            dl[u] = d;
            rk[u] = atomicAdd(&cnt[d], 1);
        } else dl[u] = -1;
    }
    __syncthreads();
    if (t < 256) excl[t] = cnt[t];
    __syncthreads();
    for (int o = 1; o < 256; o <<= 1) {
        int x = (t < 256 && t >= o) ? excl[t - o] : 0;
        __syncthreads();
        if (t < 256) excl[t] += x;
        __syncthreads();
    }
    if (t < 256) {
        int ex = excl[t] - cnt[t];
        int node = b * 256 + t;
        if (node < M) off[node] = base + ex;
        excl[t] = ex;
    }
    __syncthreads();
#pragma unroll
    for (int u = 0; u < 10; ++u) {
        if (dl[u] >= 0) {
            int lp = excl[dl[u]] + rk[u];
            if (lp < 5120) obuf[lp] = (int)(pk[u] & 0x1FFFF);
        }
    }
    __syncthreads();
    for (int i = t; i < n; i += 512) esrc[base + i] = obuf[i];
}

// ---------------- launch ----------------
extern "C" void kernel_launch(void* const* d_in, const int* in_sizes, int n_in,
                              void* d_out, int out_size, void* d_ws, size_t ws_size,
                              hipStream_t stream) {
    const float* x    = (const float*)d_in[0];
    const int*   edges = (const int*)d_in[1];
    const float* eps0 = (const float*)d_in[6];
    const float* eps1 = (const float*)d_in[11];
    const float* eps2 = (const float*)d_in[16];
    const float* B1[3] = {(const float*)d_in[3], (const float*)d_in[8], (const float*)d_in[13]};
    const float* B2[3] = {(const float*)d_in[5], (const float*)d_in[10], (const float*)d_in[15]};

    int M  = in_sizes[0] / 128;   // 100000
    int nE = in_sizes[1] / 2;     // 1600000
    const int* e_src = edges;
    const int* e_dst = edges + nE;

    char* ws = (char*)d_ws;
    size_t o = 0;
    auto alloc = [&](size_t bytes) {
        size_t p = o;
        o = (o + bytes + 511) & ~(size_t)511;
        return ws + p;
    };
    int* bucketCnt  = (int*)alloc(512 * 4);
    int* bucketBase = (int*)alloc(513 * 4);
    int* bucketCur  = (int*)alloc(512 * 4);
    int* off  = (int*)alloc((size_t)(M + 1) * 4);
    int* esrc = (int*)alloc((size_t)nE * 4);
    unsigned int* ebuf = (unsigned int*)alloc((size_t)nE * 4);

    Prep pp;
    pp.W[0] = (const float*)d_in[2];  pp.W[1] = (const float*)d_in[4];
    pp.W[2] = (const float*)d_in[7];  pp.W[3] = (const float*)d_in[9];
    pp.W[4] = (const float*)d_in[12]; pp.W[5] = (const float*)d_in[14];
    for (int m = 0; m < 6; ++m) {
        int npad = (m == 5) ? 48 : 128;
        pp.hi[m] = (unsigned short*)alloc((size_t)npad * 128 * 2);
    }
    unsigned short* xb  = (unsigned short*)alloc((size_t)M * 128 * 2);
    unsigned short* Ahi = (unsigned short*)alloc((size_t)M * 128 * 2);
    unsigned short* Hb  = (unsigned short*)alloc((size_t)M * 128 * 2);
    pp.xin = (const float4*)x;
    pp.xout = (uint2*)xb;
    pp.n4 = M * 32;
    pp.nxBlocks = (pp.n4 + 255) / 256;
    pp.dst = e_dst;
    pp.nE = nE;
    pp.bucketCnt = bucketCnt;
    (void)ws_size; (void)n_in; (void)out_size;

    int nChunk = (nE + 4095) / 4096;
    int nBk = (M + 255) / 256;

    hipMemsetAsync(bucketCnt, 0, 512 * 4, stream);
    k_prep<<<344 + pp.nxBlocks + nChunk, 256, 0, stream>>>(pp);
    bs_scan<<<1, 512, 0, stream>>>(bucketCnt, bucketBase, bucketCur, off, M, nE);
    bs_scatter<<<nChunk, 512, 0, stream>>>(e_src, e_dst, nE, bucketCur, ebuf);
    bs_build<<<nBk, 512, 0, stream>>>(ebuf, bucketBase, off, esrc, M);

    int gA = (M + 15) / 16;      // 6250
    int gG = (M + 127) / 128;    // 782

    // layer 0
    k_aggr<<<gA, 256, 0, stream>>>((const uint4*)xb, off, esrc, eps0, (uint4*)Ahi, M);
    k_mlp<8, false><<<gG, 256, 0, stream>>>(Ahi, pp.hi[0], B1[0],
                                            pp.hi[1], B2[0], Hb, nullptr, M);
    // layer 1
    k_aggr<<<gA, 256, 0, stream>>>((const uint4*)Hb, off, esrc, eps1, (uint4*)Ahi, M);
    k_mlp<8, false><<<gG, 256, 0, stream>>>(Ahi, pp.hi[2], B1[1],
                                            pp.hi[3], B2[1], Hb, nullptr, M);
    // layer 2 (log_softmax fused)
    k_aggr<<<gA, 256, 0, stream>>>((const uint4*)Hb, off, esrc, eps2, (uint4*)Ahi, M);
    k_mlp<3, true><<<gG, 256, 0, stream>>>(Ahi, pp.hi[4], B1[2],
                                           pp.hi[5], B2[2], nullptr,
                                           (float*)d_out, M);
}